// Round 4
// baseline (754.549 us; speedup 1.0000x reference)
//
#include <hip/hip_runtime.h>
#include <hip/hip_bf16.h>
#include <cstdint>

#define DEV __device__ __forceinline__
typedef __attribute__((ext_vector_type(8))) short short8;
typedef __attribute__((ext_vector_type(4))) float f32x4;
typedef unsigned short u16;

DEV float b2f(u16 u) { union { unsigned int i; float f; } x; x.i = (unsigned)u << 16; return x.f; }
DEV u16 f2b(float f) { __hip_bfloat16 h = __float2bfloat16(f); return *(u16*)&h; }
DEV float rdin(const void* p, size_t i, int isbf) {
  return isbf ? __bfloat162float(((const __hip_bfloat16*)p)[i]) : ((const float*)p)[i];
}
DEV void wrout(void* p, size_t i, float v, int isbf) {
  if (isbf) ((__hip_bfloat16*)p)[i] = __float2bfloat16(v);
  else      ((float*)p)[i] = v;
}
DEV short8 ld8(const void* p, size_t idx, int isbf) {
  if (isbf) return *(const short8*)((const u16*)p + idx);
  const float* f = (const float*)p + idx;
  float4 x = *(const float4*)f, y = *(const float4*)(f + 4);
  short8 r;
  r[0] = f2b(x.x); r[1] = f2b(x.y); r[2] = f2b(x.z); r[3] = f2b(x.w);
  r[4] = f2b(y.x); r[5] = f2b(y.y); r[6] = f2b(y.z); r[7] = f2b(y.w);
  return r;
}
// async global->LDS, 16B/lane. lds base passed wave-uniform; HW adds lane*16.
DEV void glds16(const void* g, void* ldsWaveBase) {
  __builtin_amdgcn_global_load_lds(
      (const __attribute__((address_space(1))) unsigned int*)g,
      (__attribute__((address_space(3))) unsigned int*)ldsWaveBase, 16, 0, 0);
}

__global__ __launch_bounds__(256) void detect_k(const u16* w, int* flag) {
  __shared__ int cnt[256];
  int tid = threadIdx.x, c = 0;
  for (int i = tid; i < 4096; i += 256) {
    u16 v = w[i];
    int e = (v >> 7) & 0xFF;
    if (v == 0 || (e >= 0x60 && e <= 0x9F)) c++;
  }
  cnt[tid] = c;
  __syncthreads();
  for (int s = 128; s > 0; s >>= 1) { if (tid < s) cnt[tid] += cnt[tid + s]; __syncthreads(); }
  if (tid == 0) *flag = (cnt[0] > 3600) ? 1 : 0;
}

// ---------------- A provider (weights / ws matrices, k contiguous) ----------------
struct PA {
  const void* W0; const void* W1; size_t bs; int K; unsigned rowmask; int zsel; int ws16;
  DEV size_t idx(int row, int k, int b) const {
    return (size_t)b * bs + (size_t)(row & rowmask) * K + k;
  }
  DEV const char* ad(int row, int k, int b, int zz, int isbf) const {
    const void* W = (zsel && zz == 2) ? W1 : W0;
    return (const char*)W + idx(row, k, b) * ((ws16 || isbf) ? 2 : 4);
  }
  DEV short8 l8(int row, int k, int b, int zz, int isbf) const {
    const void* W = (zsel && zz == 2) ? W1 : W0;
    return ld8(W, idx(row, k, b), ws16 ? 1 : isbf);
  }
};
// ---------------- B providers ----------------
struct PBws {  // bf16 ws tensor: X + zz*zs + row*rs + k; row = abs token or local
  const u16* X; int rs; size_t zs; int useAbs;
  DEV bool ad(int nrow, int t, int k, int zz, int, const char*& p) const {
    int r = useAbs ? t : nrow;
    p = (const char*)(X + (size_t)zz * zs + (size_t)r * rs + k);
    return true;
  }
  DEV short8 l8(int nrow, int t, int k, int zz, int) const {
    int r = useAbs ? t : nrow;
    return *(const short8*)(X + (size_t)zz * zs + (size_t)r * rs + k);
  }
};
struct PBenc {  // frames [B][3][512][512], k=(c,ky,kx), token t -> 16x16 patch
  const void* F0; const void* F1; const void* F2;
  DEV size_t idx(int t, int k) const {
    int b = t >> 10, pos = t & 1023, y = pos >> 5, x = pos & 31;
    int c = k >> 8, rem = k & 255, ky = rem >> 4, kx = rem & 15;
    return ((((size_t)(b * 3 + c) << 9) + y * 16 + ky) << 9) + x * 16 + kx;
  }
  DEV bool ad(int, int t, int k, int zz, int isbf, const char*& p) const {
    const void* F = zz == 0 ? F0 : (zz == 1 ? F1 : F2);
    p = (const char*)F + idx(t, k) * (isbf ? 2 : 4);
    return true;
  }
  DEV short8 l8(int, int t, int k, int zz, int isbf) const {
    const void* F = zz == 0 ? F0 : (zz == 1 ? F1 : F2);
    return ld8(F, idx(t, k), isbf);
  }
};
struct PBc3 {  // 3x3 SAME im2col over token-major bf16 [tok][C]; k=(tap, c)
  const u16* X; int C; int shift;
  DEV bool ad(int, int t, int k, int, int, const char*& p) const {
    int tap = k >> shift, c0 = k & (C - 1);
    int dy = tap / 3, dx = tap - dy * 3;
    int pos = t & 1023, y = pos >> 5, x = pos & 31;
    int iy = y + dy - 1, ix = x + dx - 1;
    if ((unsigned)iy >= 32u || (unsigned)ix >= 32u) return false;
    p = (const char*)(X + (size_t)(((t >> 10) * 1024) + iy * 32 + ix) * C + c0);
    return true;
  }
  DEV short8 l8(int nrow, int t, int k, int zz, int isbf) const {
    const char* p;
    if (!ad(nrow, t, k, zz, isbf, p)) { short8 z = {0,0,0,0,0,0,0,0}; return z; }
    return *(const short8*)p;
  }
};

struct Epi {  // mode 0: tok-major bf16; 1: val (memv scatter / fused); 2: fp32 partial
  int mode; u16* o16; u16* o16b; float* o32;
  size_t zs; int ts; int moff; int mmax;
  size_t sstride; int ntot;
  const void* bias; const void* bias2; int bzsel;
  const void* maskA; const void* maskB;
  float scale; int relu; int doexp; int nbase;
  DEV void store(int m, int nloc, int z, float v, int isbf) const {
    if (m >= mmax) return;
    if (mode == 2) { o32[(size_t)z * sstride + (size_t)m * ntot + nloc] = v; return; }
    v *= scale;
    if (bias) v += rdin((bzsel && z == 2) ? bias2 : bias, m, isbf);
    if (doexp) v = __expf(v);
    int t = nbase + nloc, b = t >> 10, pos = t & 1023;
    if (mode == 1) {
      if (z < 2) {
        const void* mk = z ? maskB : maskA;
        v *= rdin(mk, ((size_t)(b * 512 + (pos >> 5) * 16) << 9) + (pos & 31) * 16, isbf);
        o16[((size_t)(b * 256 + m)) * 2048 + (size_t)z * 1024 + pos] = f2b(v);
      } else {
        o16b[(size_t)t * 512 + m] = f2b(v);
      }
      return;
    }
    if (relu) v = fmaxf(v, 0.f);
    o16[(size_t)z * zs + (size_t)t * ts + moff + m] = f2b(v);
  }
};

// ------- MFMA GEMM: 128x128 tile, BK=64, 4 waves, each wave 64x64 (4x4 frags) -------
template <class PB>
__global__ __launch_bounds__(256) void mg(PA pa, PB pb, Epi ep, int ktiles, int zIsK,
                                          int nbaseProv, const int* dflag) {
  __shared__ u16 As[128 * 64];
  __shared__ u16 Bs[128 * 64];
  int isbf = *dflag;
  int tid = threadIdx.x, lane = tid & 63, wv = tid >> 6;
  int col16 = lane & 15, quad = lane >> 4;
  int wm = wv >> 1, wn = wv & 1;
  int bz = blockIdx.z;
  int zz = zIsK ? 0 : bz;
  int kbase = zIsK ? bz * ktiles * 64 : 0;
  int n0 = blockIdx.x * 128, m0 = blockIdx.y * 128;
  int bA = (nbaseProv + n0) >> 10;
  int srow = tid >> 3, sslot = tid & 7;
  char* AsW = (char*)As + (size_t)(tid >> 6) * 1024;  // wave-uniform DMA base
  char* BsW = (char*)Bs + (size_t)(tid >> 6) * 1024;
  int wslot = (tid & 63) * 16;                        // this lane's slot within wave chunk

  f32x4 acc[4][4];
#pragma unroll
  for (int mt = 0; mt < 4; mt++)
#pragma unroll
    for (int nt = 0; nt < 4; nt++)
#pragma unroll
      for (int r = 0; r < 4; r++) acc[mt][nt][r] = 0.f;

  for (int kt = 0; kt < ktiles; kt++) {
    int k0 = kbase + kt * 64;
    if (isbf) {
#pragma unroll
      for (int g = 0; g < 4; g++) {
        int row = g * 32 + srow;
        int j = sslot ^ (row & 7);
        glds16(pa.ad(m0 + row, k0 + j * 8, bA, zz, isbf), AsW + g * 4096);
      }
#pragma unroll
      for (int g = 0; g < 4; g++) {
        int row = g * 32 + srow;
        int j = sslot ^ (row & 7);
        const char* p;
        bool ok = pb.ad(row, nbaseProv + n0 + row, k0 + j * 8, zz, isbf, p);
        if (ok) glds16(p, BsW + g * 4096);
        else { short8 z8 = {0,0,0,0,0,0,0,0}; *(short8*)((char*)Bs + g * 4096 + tid * 16) = z8; }
      }
    } else {
#pragma unroll
      for (int g = 0; g < 4; g++) {
        int row = g * 32 + srow;
        int j = sslot ^ (row & 7);
        short8 v = pa.l8(m0 + row, k0 + j * 8, bA, zz, isbf);
        *(short8*)((char*)As + g * 4096 + tid * 16) = v;
        short8 w = pb.l8(row, nbaseProv + n0 + row, k0 + j * 8, zz, isbf);
        *(short8*)((char*)Bs + g * 4096 + tid * 16) = w;
      }
    }
    __syncthreads();
#pragma unroll
    for (int s = 0; s < 2; s++) {
      short8 af[4], bf[4];
#pragma unroll
      for (int mt = 0; mt < 4; mt++) {
        int row = wm * 64 + mt * 16 + col16;
        af[mt] = *(const short8*)&As[row * 64 + (((s * 4 + quad) ^ (col16 & 7)) << 3)];
      }
#pragma unroll
      for (int nt = 0; nt < 4; nt++) {
        int row = wn * 64 + nt * 16 + col16;
        bf[nt] = *(const short8*)&Bs[row * 64 + (((s * 4 + quad) ^ (col16 & 7)) << 3)];
      }
#pragma unroll
      for (int mt = 0; mt < 4; mt++)
#pragma unroll
        for (int nt = 0; nt < 4; nt++)
          acc[mt][nt] = __builtin_amdgcn_mfma_f32_16x16x32_bf16(af[mt], bf[nt], acc[mt][nt], 0, 0, 0);
    }
    __syncthreads();
  }
#pragma unroll
  for (int mt = 0; mt < 4; mt++)
#pragma unroll
    for (int nt = 0; nt < 4; nt++)
#pragma unroll
      for (int r = 0; r < 4; r++) {
        int m = m0 + wm * 64 + mt * 16 + quad * 4 + r;
        int nloc = n0 + wn * 64 + nt * 16 + col16;
        ep.store(m, nloc, bz, acc[mt][nt][r], isbf);
      }
}

// reduce split-K partials + transpose to token-major bf16 with epilogue
__global__ __launch_bounds__(256) void redux_k(const float* part, int ns, size_t sstr,
                                               int ntot, u16* out, int ostride, int moff,
                                               const void* bias, const float* nscale,
                                               int tokbase, int relu, const int* dflag) {
  __shared__ float T[64][65];
  int t = threadIdx.x;
  int tn0 = blockIdx.x * 64, tm0 = blockIdx.y * 64;
#pragma unroll
  for (int r = 0; r < 16; r++) {
    int mi = r * 4 + (t >> 6), tj = t & 63;
    float v = 0.f;
    for (int s = 0; s < ns; s++) v += part[(size_t)s * sstr + (size_t)(tm0 + mi) * ntot + tn0 + tj];
    T[mi][tj] = v;
  }
  __syncthreads();
  int isbf = *dflag;
#pragma unroll
  for (int r = 0; r < 16; r++) {
    int tj = r * 4 + (t >> 6), mi = t & 63;
    float v = T[mi][tj];
    if (bias) v += rdin(bias, tm0 + mi, isbf);
    if (nscale) v *= nscale[tokbase + tn0 + tj];
    if (relu) v = fmaxf(v, 0.f);
    out[(size_t)(tokbase + tn0 + tj) * ostride + moff + tm0 + mi] = f2b(v);
  }
}

// conv3 weight reorder: dst[m][tap*C+c] = src[(m*C+c)*9 + tap]
__global__ __launch_bounds__(256) void wreorder_k(const void* src, u16* dst, int C,
                                                  int total, const int* dflag) {
  int idx = blockIdx.x * 256 + threadIdx.x;
  if (idx >= total) return;
  int isbf = *dflag;
  int nine_c = 9 * C;
  int m = idx / nine_c; int r = idx - m * nine_c;
  int tp = r / C; int c = r - tp * C;
  dst[idx] = f2b(rdin(src, (size_t)(m * C + c) * 9 + tp, isbf));
}

// mask + l2norm over 64 key channels; 3 frames via blockIdx.y
__global__ __launch_bounds__(256) void keyfix_k(const u16* kraw3, const void* mA,
                                                const void* mB, u16* memk, u16* qk,
                                                const int* dflag) {
  int isbf = *dflag;
  int z = blockIdx.y;
  int n = blockIdx.x * 256 + threadIdx.x;
  int b = n >> 10, pos = n & 1023;
  float mv = 1.f;
  if (z == 0) mv = rdin(mA, ((size_t)(b * 512 + (pos >> 5) * 16) << 9) + (pos & 31) * 16, isbf);
  else if (z == 1) mv = rdin(mB, ((size_t)(b * 512 + (pos >> 5) * 16) << 9) + (pos & 31) * 16, isbf);
  const u16* src = kraw3 + ((size_t)z * 8192 + n) * 64;
  float v[64], ss = 0.f;
#pragma unroll
  for (int c = 0; c < 64; c++) { v[c] = b2f(src[c]) * mv; ss += v[c] * v[c]; }
  float inv = 1.f / fmaxf(sqrtf(ss), 1e-12f);
  u16* dst = (z < 2) ? memk + (size_t)(b * 2048 + z * 1024 + pos) * 64 : qk + (size_t)n * 64;
#pragma unroll
  for (int c = 0; c < 64; c++) dst[c] = f2b(v[c] * inv);
}

// row sums of exp'ed P (bf16 [4096][2048]) -> 1/sum
__global__ __launch_bounds__(256) void stats_k(const u16* P, float* rsinv) {
  int tid = threadIdx.x, lane = tid & 63, wv = tid >> 6;
  int row = blockIdx.x * 4 + wv;
  const u16* p = P + (size_t)row * 2048;
  float s = 0.f;
#pragma unroll
  for (int c = 0; c < 4; c++) {
    short8 v = *(const short8*)(p + c * 512 + lane * 8);
#pragma unroll
    for (int j = 0; j < 8; j++) s += b2f((u16)v[j]);
  }
#pragma unroll
  for (int off = 32; off > 0; off >>= 1) s += __shfl_down(s, off);
  if (lane == 0) rsinv[row] = 1.f / s;
}

__global__ __launch_bounds__(256) void repcls_k(const u16* decf, const void* cwgt,
                                                const void* cbias, void* out_rep,
                                                float* logits, const int* dflag) {
  int isbf = *dflag;
  int tid = threadIdx.x, lane = tid & 63, wv = tid >> 6;
  int tok = blockIdx.x * 4 + wv;
  int b = tok >> 10, pos = tok & 1023;
  const u16* src = decf + (size_t)tok * 256;
  int c0 = lane * 4;
  float v[4], ss = 0.f, a0 = 0.f, a1 = 0.f;
#pragma unroll
  for (int j = 0; j < 4; j++) {
    float x = b2f(src[c0 + j]);
    v[j] = x; ss += x * x;
    a0 = fmaf(x, rdin(cwgt, c0 + j, isbf), a0);
    a1 = fmaf(x, rdin(cwgt, 256 + c0 + j, isbf), a1);
  }
#pragma unroll
  for (int off = 32; off > 0; off >>= 1) {
    ss += __shfl_down(ss, off); a0 += __shfl_down(a0, off); a1 += __shfl_down(a1, off);
  }
  ss = __shfl(ss, 0); a0 = __shfl(a0, 0); a1 = __shfl(a1, 0);
  float inv = 1.f / fmaxf(sqrtf(ss), 1e-12f);
#pragma unroll
  for (int j = 0; j < 4; j++)
    wrout(out_rep, ((size_t)(b * 256 + c0 + j) << 10) + pos, v[j] * inv, isbf);
  if (lane == 0) {
    logits[((size_t)(b * 2) << 10) + pos]     = a0 + rdin(cbias, 0, isbf);
    logits[((size_t)(b * 2 + 1) << 10) + pos] = a1 + rdin(cbias, 1, isbf);
  }
}

__global__ __launch_bounds__(256) void resize_k(const float* logits, void* out,
                                                size_t ebase, const int* dflag) {
  int isbf = *dflag;
  int idx = blockIdx.x * 256 + threadIdx.x;
  int ox = idx & 511, oy = (idx >> 9) & 511, c = (idx >> 18) & 1, b = idx >> 19;
  float fy = (oy + 0.5f) * 0.0625f - 0.5f;
  float fx = (ox + 0.5f) * 0.0625f - 0.5f;
  int y0 = (int)floorf(fy), x0 = (int)floorf(fx);
  float wy = fy - y0, wx = fx - x0;
  int y0c = max(y0, 0), y1c = min(y0 + 1, 31);
  int x0c = max(x0, 0), x1c = min(x0 + 1, 31);
  const float* L = logits + ((size_t)(b * 2 + c) << 10);
  float v00 = L[y0c * 32 + x0c], v01 = L[y0c * 32 + x1c];
  float v10 = L[y1c * 32 + x0c], v11 = L[y1c * 32 + x1c];
  float v = (1.f - wy) * ((1.f - wx) * v00 + wx * v01) + wy * ((1.f - wx) * v10 + wx * v11);
  wrout(out, ebase + (size_t)idx, v, isbf);
}

extern "C" void kernel_launch(void* const* d_in, const int* in_sizes, int n_in,
                              void* d_out, int out_size, void* d_ws, size_t ws_size,
                              hipStream_t stream) {
  const void* query  = d_in[0];  const void* prev   = d_in[1];
  const void* prevM  = d_in[2];  const void* first  = d_in[3];
  const void* firstM = d_in[4];  const void* encQw  = d_in[5];
  const void* encQb  = d_in[6];  const void* encMw  = d_in[7];
  const void* encMb  = d_in[8];  const void* keyW   = d_in[9];
  const void* keyB   = d_in[10]; const void* valW   = d_in[11];
  const void* valB   = d_in[12]; const void* dec1W  = d_in[13];
  const void* dec1B  = d_in[14]; const void* dec2W  = d_in[15];
  const void* dec2B  = d_in[16]; const void* clsW   = d_in[17];
  const void* clsB   = d_in[18];

  // ws layout (u16 units); total 28,557,328 u16 = 54.5 MB
  u16* W = (u16*)d_ws;
  u16* fused = W;                          // [8192][512]
  u16* memv  = W + 4194304;                // [8][256][2048]
  u16* memk  = W + 8388608;                // [8][2048][64]
  u16* qk    = W + 9437184;                // [8192][64]
  u16* wr1   = W + 9961472;                // [256][4608]
  u16* wr2   = W + 11141120;               // [256][2304]
  float* rsinv  = (float*)(W + 11730944);  // 8192 f32
  float* logits = (float*)(W + 11747328);  // 16384 f32
  int* dflag = (int*)(W + 11780096);
  u16* E = W + 11780112;
  u16* feat3 = E;                          // [3][8192][512]
  u16* kraw3 = E + 12582912;               // [3][8192][64]
  u16* P     = E;                          // [4096][2048] per group
  float* partR = (float*)(E + 8388608);    // [4][256][4096] f32
  float* partD = (float*)E;                // [2][256][8192] f32
  u16* dbuf  = E + 8388608;                // [8192][256]
  u16* decf  = E + 10485760;               // [8192][256]

  dim3 blk(256);
  detect_k<<<dim3(1), blk, 0, stream>>>((const u16*)encQw, dflag);
  wreorder_k<<<dim3(4608), blk, 0, stream>>>(dec1W, wr1, 512, 256 * 4608, dflag);
  wreorder_k<<<dim3(2304), blk, 0, stream>>>(dec2W, wr2, 256, 256 * 2304, dflag);

  // encode: feat3[z][tok][512], z = {first, prev, query}
  {
    PA a{encMw, encQw, 0, 768, 0xFFFFFFFFu, 1, 0};
    PBenc b{first, prev, query};
    Epi e{0, feat3, 0, 0, (size_t)8192 * 512, 512, 0, 512, 0, 0,
          encMb, encQb, 1, 0, 0, 1.f, 1, 0, 0};
    mg<PBenc><<<dim3(64, 4, 3), blk, 0, stream>>>(a, b, e, 12, 0, 0, dflag);
  }
  // key: kraw3[z][tok][64]
  {
    PA a{keyW, 0, 0, 512, 63u, 0, 0};
    PBws b{feat3, 512, (size_t)8192 * 512, 1};
    Epi e{0, kraw3, 0, 0, (size_t)8192 * 64, 64, 0, 64, 0, 0,
          keyB, 0, 0, 0, 0, 1.f, 0, 0, 0};
    mg<PBws><<<dim3(64, 1, 3), blk, 0, stream>>>(a, b, e, 8, 0, 0, dflag);
  }
  // val: z<2 -> memv (masked, m-major), z=2 -> fused[:, 0..255]
  {
    PA a{valW, 0, 0, 512, 0xFFFFFFFFu, 0, 0};
    PBws b{feat3, 512, (size_t)8192 * 512, 1};
    Epi e{1, memv, fused, 0, 0, 0, 0, 256, 0, 0,
          valB, 0, 0, firstM, prevM, 1.f, 0, 0, 0};
    mg<PBws><<<dim3(64, 2, 3), blk, 0, stream>>>(a, b, e, 8, 0, 0, dflag);
  }
  keyfix_k<<<dim3(32, 3), blk, 0, stream>>>(kraw3, firstM, prevM, memk, qk, dflag);

  // attention in 2 groups of 4 batches
  for (int g = 0; g < 2; g++) {
    int nb = g * 4096;
    {  // S: P[tloc][m] = exp(0.125 * qk[t,:].memk[b,m,:])
      PA a{memk, 0, 131072, 64, 0xFFFFFFFFu, 0, 1};
      PBws b{qk, 64, 0, 1};
      Epi e{0, P, 0, 0, 0, 2048, 0, 1 << 30, 0, 0,
            0, 0, 0, 0, 0, 0.125f, 0, 1, 0};
      mg<PBws><<<dim3(32, 16, 1), blk, 0, stream>>>(a, b, e, 1, 0, nb, dflag);
    }
    stats_k<<<dim3(1024), blk, 0, stream>>>(P, rsinv + nb);
    {  // read: partR[s][c][tloc] = sum_m memv[b][c][m] * P[tloc][m]  (split-K x4)
      PA a{memv, 0, 524288, 2048, 0xFFFFFFFFu, 0, 1};
      PBws b{P, 2048, 0, 0};
      Epi e{2, 0, 0, partR, 0, 0, 0, 1 << 30, (size_t)256 * 4096, 4096,
            0, 0, 0, 0, 0, 1.f, 0, 0, 0};
      mg<PBws><<<dim3(32, 2, 4), blk, 0, stream>>>(a, b, e, 8, 1, nb, dflag);
    }
    redux_k<<<dim3(64, 4), blk, 0, stream>>>(partR, 4, (size_t)256 * 4096, 4096,
                                             fused, 512, 256, 0, rsinv, nb, 0, dflag);
  }

  // dec1 (split-K x2) -> dbuf
  {
    PA a{wr1, 0, 0, 4608, 0xFFFFFFFFu, 0, 1};
    PBc3 b{fused, 512, 9};
    Epi e{2, 0, 0, partD, 0, 0, 0, 1 << 30, (size_t)256 * 8192, 8192,
          0, 0, 0, 0, 0, 1.f, 0, 0, 0};
    mg<PBc3><<<dim3(64, 2, 2), blk, 0, stream>>>(a, b, e, 36, 1, 0, dflag);
  }
  redux_k<<<dim3(128, 4), blk, 0, stream>>>(partD, 2, (size_t)256 * 8192, 8192,
                                            dbuf, 256, 0, dec1B, 0, 0, 1, dflag);
  // dec2 (split-K x2) -> decf
  {
    PA a{wr2, 0, 0, 2304, 0xFFFFFFFFu, 0, 1};
    PBc3 b{dbuf, 256, 8};
    Epi e{2, 0, 0, partD, 0, 0, 0, 1 << 30, (size_t)256 * 8192, 8192,
          0, 0, 0, 0, 0, 1.f, 0, 0, 0};
    mg<PBc3><<<dim3(64, 2, 2), blk, 0, stream>>>(a, b, e, 18, 1, 0, dflag);
  }
  redux_k<<<dim3(128, 4), blk, 0, stream>>>(partD, 2, (size_t)256 * 8192, 8192,
                                            decf, 256, 0, dec2B, 0, 0, 1, dflag);

  repcls_k<<<dim3(2048), blk, 0, stream>>>(decf, clsW, clsB, d_out, logits, dflag);
  resize_k<<<dim3(16384), blk, 0, stream>>>(logits, d_out, (size_t)2097152, dflag);
}

// Round 5
// 713.427 us; speedup vs baseline: 1.0576x; 1.0576x over previous
//
#include <hip/hip_runtime.h>
#include <hip/hip_bf16.h>
#include <cstdint>

#define DEV __device__ __forceinline__
typedef __attribute__((ext_vector_type(8))) short short8;
typedef __attribute__((ext_vector_type(4))) float f32x4;
typedef unsigned short u16;

DEV float b2f(u16 u) { union { unsigned int i; float f; } x; x.i = (unsigned)u << 16; return x.f; }
DEV u16 f2b(float f) { __hip_bfloat16 h = __float2bfloat16(f); return *(u16*)&h; }
DEV float rdin(const void* p, size_t i, int isbf) {
  return isbf ? __bfloat162float(((const __hip_bfloat16*)p)[i]) : ((const float*)p)[i];
}
DEV void wrout(void* p, size_t i, float v, int isbf) {
  if (isbf) ((__hip_bfloat16*)p)[i] = __float2bfloat16(v);
  else      ((float*)p)[i] = v;
}
DEV short8 ld8(const void* p, size_t idx, int isbf) {
  if (isbf) return *(const short8*)((const u16*)p + idx);
  const float* f = (const float*)p + idx;
  float4 x = *(const float4*)f, y = *(const float4*)(f + 4);
  short8 r;
  r[0] = f2b(x.x); r[1] = f2b(x.y); r[2] = f2b(x.z); r[3] = f2b(x.w);
  r[4] = f2b(y.x); r[5] = f2b(y.y); r[6] = f2b(y.z); r[7] = f2b(y.w);
  return r;
}

__global__ __launch_bounds__(256) void detect_k(const u16* w, int* flag) {
  __shared__ int cnt[256];
  int tid = threadIdx.x, c = 0;
  for (int i = tid; i < 4096; i += 256) {
    u16 v = w[i];
    int e = (v >> 7) & 0xFF;
    if (v == 0 || (e >= 0x60 && e <= 0x9F)) c++;
  }
  cnt[tid] = c;
  __syncthreads();
  for (int s = 128; s > 0; s >>= 1) { if (tid < s) cnt[tid] += cnt[tid + s]; __syncthreads(); }
  if (tid == 0) *flag = (cnt[0] > 3600) ? 1 : 0;
}

// ---------------- A provider ----------------
struct PA {  // W0/W1 weights or ws16 matrices; row-split (keyval) or z-select (enc)
  const void* W0; const void* W1; size_t bs; int K; int rowsplit; int zsel; int ws16; int rowmax1;
  DEV short8 l8(int row, int k, int b, int zz, int isbf) const {
    const void* W = W0; int r = row;
    if (zsel && zz == 2) W = W1;
    else if (rowsplit && row >= rowsplit) { W = W1; r = row - rowsplit; if (r > rowmax1) r = rowmax1; }
    return ld8(W, (size_t)b * bs + (size_t)r * K + k, ws16 ? 1 : isbf);
  }
};
// ---------------- B providers ----------------
struct PBws {  // bf16 ws tensor: X + zz*zs + (t - tbase)*rs + k
  const u16* X; int rs; size_t zs; int tbase;
  DEV short8 l8(int t, int k, int zz, int) const {
    return *(const short8*)(X + (size_t)zz * zs + (size_t)(t - tbase) * rs + k);
  }
};
struct PBenc {  // frames [B][3][512][512], k=(c,ky,kx), token t -> 16x16 patch
  const void* F0; const void* F1; const void* F2;
  DEV short8 l8(int t, int k, int zz, int isbf) const {
    const void* F = zz == 0 ? F0 : (zz == 1 ? F1 : F2);
    int b = t >> 10, pos = t & 1023, y = pos >> 5, x = pos & 31;
    int c = k >> 8, rem = k & 255, ky = rem >> 4, kx = rem & 15;
    return ld8(F, ((((size_t)(b * 3 + c) << 9) + y * 16 + ky) << 9) + x * 16 + kx, isbf);
  }
};
struct PBc3 {  // 3x3 SAME im2col over token-major bf16 [tok][C]; k=(tap, c)
  const u16* X; int C; int shift;
  DEV short8 l8(int t, int k, int, int) const {
    int tap = k >> shift, c0 = k & (C - 1);
    int dy = tap / 3, dx = tap - dy * 3;
    int pos = t & 1023, y = pos >> 5, x = pos & 31;
    int iy = y + dy - 1, ix = x + dx - 1;
    if ((unsigned)iy >= 32u || (unsigned)ix >= 32u) { short8 z = {0,0,0,0,0,0,0,0}; return z; }
    return *(const short8*)(X + (size_t)(((t >> 10) * 1024) + iy * 32 + ix) * C + c0);
  }
};

struct Epi {  // 0: tok-major bf16; 1: key+val scatter; 2: fp32 slab; 3: fp32 atomicAdd
  int mode; u16 *o16, *o16b, *o16c; float* o32;
  size_t zs; int ts, moff, mmax, tsub;
  size_t sstride; int ntot;
  const void *bias, *bias2; int bzsel;
  const void *maskA, *maskB;
  float scale; int relu, doexp;
  DEV void store(int m, int t, int z, float v, int isbf) const {
    if (m >= mmax) return;
    if (mode == 2) { o32[(size_t)z * sstride + (size_t)m * ntot + (t - tsub)] = v; return; }
    if (mode == 3) { atomicAdd(o32 + (size_t)m * ntot + (t - tsub), v); return; }
    v *= scale;
    if (mode == 1) {
      int b = t >> 10, pos = t & 1023;
      if (m < 256) {
        v += rdin(bias, m, isbf);
        if (z < 2) {
          const void* mk = z ? maskB : maskA;
          v *= rdin(mk, ((size_t)(b * 512 + (pos >> 5) * 16) << 9) + (pos & 31) * 16, isbf);
          o16[((size_t)(b * 256 + m)) * 2048 + (size_t)z * 1024 + pos] = f2b(v);
        } else {
          o16b[(size_t)t * 512 + m] = f2b(v);
        }
      } else {
        v += rdin(bias2, m - 256, isbf);
        o16c[((size_t)z * 8192 + t) * 64 + (m - 256)] = f2b(v);
      }
      return;
    }
    if (bias) v += rdin((bzsel && z == 2) ? bias2 : bias, m, isbf);
    if (doexp) v = __expf(v);
    if (relu) v = fmaxf(v, 0.f);
    o16[(size_t)z * zs + (size_t)(t - tsub) * ts + moff + m] = f2b(v);
  }
};

// ---- MFMA GEMM: 128x128 tile, BK=64, 4 waves (each 64x64), register-prefetch K-loop ----
template <class PB>
__global__ __launch_bounds__(256) void mg(PA pa, PB pb, Epi ep, int ktiles, int zIsK,
                                          int nbase, const int* dflag) {
  __shared__ u16 As[128 * 64];
  __shared__ u16 Bs[128 * 64];
  int isbf = *dflag;
  int tid = threadIdx.x, lane = tid & 63;
  int col16 = lane & 15, quad = lane >> 4;
  int wv = tid >> 6, wm = wv >> 1, wn = wv & 1;
  int bz = blockIdx.z;
  int zz = zIsK ? 0 : bz;
  int kbase = zIsK ? bz * ktiles * 64 : 0;
  int n0 = blockIdx.x * 128, m0 = blockIdx.y * 128;
  int bA = (nbase + n0) >> 10;

  f32x4 acc[4][4];
#pragma unroll
  for (int mt = 0; mt < 4; mt++)
#pragma unroll
    for (int nt = 0; nt < 4; nt++)
#pragma unroll
      for (int r = 0; r < 4; r++) acc[mt][nt][r] = 0.f;

  int arow[4], aj[4];
#pragma unroll
  for (int g = 0; g < 4; g++) {
    int id = g * 256 + tid;
    arow[g] = id >> 3;
    aj[g] = (id & 7) ^ (arow[g] & 7);  // XOR swizzle: conflict-free frag reads
  }

  short8 ra[4], rb[4];
#pragma unroll
  for (int g = 0; g < 4; g++) {
    ra[g] = pa.l8(m0 + arow[g], kbase + aj[g] * 8, bA, zz, isbf);
    rb[g] = pb.l8(nbase + n0 + arow[g], kbase + aj[g] * 8, zz, isbf);
  }

  for (int kt = 0; kt < ktiles; kt++) {
    if (kt) __syncthreads();
#pragma unroll
    for (int g = 0; g < 4; g++) {
      *(short8*)&As[(size_t)(g * 256 + tid) * 8] = ra[g];
      *(short8*)&Bs[(size_t)(g * 256 + tid) * 8] = rb[g];
    }
    __syncthreads();
    if (kt + 1 < ktiles) {  // prefetch next tile into regs under the MFMA block
      int kn = kbase + (kt + 1) * 64;
#pragma unroll
      for (int g = 0; g < 4; g++) {
        ra[g] = pa.l8(m0 + arow[g], kn + aj[g] * 8, bA, zz, isbf);
        rb[g] = pb.l8(nbase + n0 + arow[g], kn + aj[g] * 8, zz, isbf);
      }
    }
#pragma unroll
    for (int s = 0; s < 2; s++) {
      short8 af[4], bf[4];
      int cs = ((s * 4 + quad) ^ (col16 & 7)) << 3;
#pragma unroll
      for (int mt = 0; mt < 4; mt++)
        af[mt] = *(const short8*)&As[(wm * 64 + mt * 16 + col16) * 64 + cs];
#pragma unroll
      for (int nt = 0; nt < 4; nt++)
        bf[nt] = *(const short8*)&Bs[(wn * 64 + nt * 16 + col16) * 64 + cs];
#pragma unroll
      for (int mt = 0; mt < 4; mt++)
#pragma unroll
        for (int nt = 0; nt < 4; nt++)
          acc[mt][nt] = __builtin_amdgcn_mfma_f32_16x16x32_bf16(af[mt], bf[nt], acc[mt][nt], 0, 0, 0);
    }
  }
#pragma unroll
  for (int mt = 0; mt < 4; mt++)
#pragma unroll
    for (int nt = 0; nt < 4; nt++)
#pragma unroll
      for (int r = 0; r < 4; r++) {
        int m = m0 + wm * 64 + mt * 16 + quad * 4 + r;
        int t = nbase + n0 + wn * 64 + nt * 16 + col16;
        ep.store(m, t, bz, acc[mt][nt][r], isbf);
      }
}

// reduce split-K fp32 slabs + transpose to token-major bf16 with epilogue
__global__ __launch_bounds__(256) void redux_k(const float* part, int ns, size_t sstr,
                                               int ntot, u16* out, int ostride, int moff,
                                               const void* bias, const float* nscale,
                                               int tokbase, int relu, const int* dflag) {
  __shared__ float T[64][65];
  int t = threadIdx.x;
  int tn0 = blockIdx.x * 64, tm0 = blockIdx.y * 64;
#pragma unroll
  for (int r = 0; r < 16; r++) {
    int mi = r * 4 + (t >> 6), tj = t & 63;
    float v = 0.f;
    for (int s = 0; s < ns; s++) v += part[(size_t)s * sstr + (size_t)(tm0 + mi) * ntot + tn0 + tj];
    T[mi][tj] = v;
  }
  __syncthreads();
  int isbf = *dflag;
#pragma unroll
  for (int r = 0; r < 16; r++) {
    int tj = r * 4 + (t >> 6), mi = t & 63;
    float v = T[mi][tj];
    if (bias) v += rdin(bias, tm0 + mi, isbf);
    if (nscale) v *= nscale[tokbase + tn0 + tj];
    if (relu) v = fmaxf(v, 0.f);
    out[(size_t)(tokbase + tn0 + tj) * ostride + moff + tm0 + mi] = f2b(v);
  }
}

__global__ __launch_bounds__(256) void zero_k(float4* p) {
  p[(size_t)blockIdx.x * 256 + threadIdx.x] = float4{0.f, 0.f, 0.f, 0.f};
}

// conv3 weight reorder: dst[m][tap*C+c] = src[(m*C+c)*9 + tap]
__global__ __launch_bounds__(256) void wreorder_k(const void* src, u16* dst, int C,
                                                  int total, const int* dflag) {
  int idx = blockIdx.x * 256 + threadIdx.x;
  if (idx >= total) return;
  int isbf = *dflag;
  int nine_c = 9 * C;
  int m = idx / nine_c; int r = idx - m * nine_c;
  int tp = r / C; int c = r - tp * C;
  dst[idx] = f2b(rdin(src, (size_t)(m * C + c) * 9 + tp, isbf));
}

// mask + l2norm over 64 key channels; 3 frames via blockIdx.y
__global__ __launch_bounds__(256) void keyfix_k(const u16* kraw3, const void* mA,
                                                const void* mB, u16* memk, u16* qk,
                                                const int* dflag) {
  int isbf = *dflag;
  int z = blockIdx.y;
  int n = blockIdx.x * 256 + threadIdx.x;
  int b = n >> 10, pos = n & 1023;
  float mv = 1.f;
  if (z == 0) mv = rdin(mA, ((size_t)(b * 512 + (pos >> 5) * 16) << 9) + (pos & 31) * 16, isbf);
  else if (z == 1) mv = rdin(mB, ((size_t)(b * 512 + (pos >> 5) * 16) << 9) + (pos & 31) * 16, isbf);
  const u16* src = kraw3 + ((size_t)z * 8192 + n) * 64;
  float v[64], ss = 0.f;
#pragma unroll
  for (int c = 0; c < 64; c++) { v[c] = b2f(src[c]) * mv; ss += v[c] * v[c]; }
  float inv = 1.f / fmaxf(sqrtf(ss), 1e-12f);
  u16* dst = (z < 2) ? memk + (size_t)(b * 2048 + z * 1024 + pos) * 64 : qk + (size_t)n * 64;
#pragma unroll
  for (int c = 0; c < 64; c++) dst[c] = f2b(v[c] * inv);
}

// row sums of exp'ed P (bf16 [4096][2048]) -> 1/sum
__global__ __launch_bounds__(256) void stats_k(const u16* P, float* rsinv) {
  int tid = threadIdx.x, lane = tid & 63, wv = tid >> 6;
  int row = blockIdx.x * 4 + wv;
  const u16* p = P + (size_t)row * 2048;
  float s = 0.f;
#pragma unroll
  for (int c = 0; c < 4; c++) {
    short8 v = *(const short8*)(p + c * 512 + lane * 8);
#pragma unroll
    for (int j = 0; j < 8; j++) s += b2f((u16)v[j]);
  }
#pragma unroll
  for (int off = 32; off > 0; off >>= 1) s += __shfl_down(s, off);
  if (lane == 0) rsinv[row] = 1.f / s;
}

__global__ __launch_bounds__(256) void repcls_k(const u16* decf, const void* cwgt,
                                                const void* cbias, void* out_rep,
                                                float* logits, const int* dflag) {
  int isbf = *dflag;
  int tid = threadIdx.x, lane = tid & 63, wv = tid >> 6;
  int tok = blockIdx.x * 4 + wv;
  int b = tok >> 10, pos = tok & 1023;
  const u16* src = decf + (size_t)tok * 256;
  int c0 = lane * 4;
  float v[4], ss = 0.f, a0 = 0.f, a1 = 0.f;
#pragma unroll
  for (int j = 0; j < 4; j++) {
    float x = b2f(src[c0 + j]);
    v[j] = x; ss += x * x;
    a0 = fmaf(x, rdin(cwgt, c0 + j, isbf), a0);
    a1 = fmaf(x, rdin(cwgt, 256 + c0 + j, isbf), a1);
  }
#pragma unroll
  for (int off = 32; off > 0; off >>= 1) {
    ss += __shfl_down(ss, off); a0 += __shfl_down(a0, off); a1 += __shfl_down(a1, off);
  }
  ss = __shfl(ss, 0); a0 = __shfl(a0, 0); a1 = __shfl(a1, 0);
  float inv = 1.f / fmaxf(sqrtf(ss), 1e-12f);
#pragma unroll
  for (int j = 0; j < 4; j++)
    wrout(out_rep, ((size_t)(b * 256 + c0 + j) << 10) + pos, v[j] * inv, isbf);
  if (lane == 0) {
    logits[((size_t)(b * 2) << 10) + pos]     = a0 + rdin(cbias, 0, isbf);
    logits[((size_t)(b * 2 + 1) << 10) + pos] = a1 + rdin(cbias, 1, isbf);
  }
}

__global__ __launch_bounds__(256) void resize_k(const float* logits, void* out,
                                                size_t ebase, const int* dflag) {
  int isbf = *dflag;
  int idx = blockIdx.x * 256 + threadIdx.x;
  int ox = idx & 511, oy = (idx >> 9) & 511, c = (idx >> 18) & 1, b = idx >> 19;
  float fy = (oy + 0.5f) * 0.0625f - 0.5f;
  float fx = (ox + 0.5f) * 0.0625f - 0.5f;
  int y0 = (int)floorf(fy), x0 = (int)floorf(fx);
  float wy = fy - y0, wx = fx - x0;
  int y0c = max(y0, 0), y1c = min(y0 + 1, 31);
  int x0c = max(x0, 0), x1c = min(x0 + 1, 31);
  const float* L = logits + ((size_t)(b * 2 + c) << 10);
  float v00 = L[y0c * 32 + x0c], v01 = L[y0c * 32 + x1c];
  float v10 = L[y1c * 32 + x0c], v11 = L[y1c * 32 + x1c];
  float v = (1.f - wy) * ((1.f - wx) * v00 + wx * v01) + wy * ((1.f - wx) * v10 + wx * v11);
  wrout(out, ebase + (size_t)idx, v, isbf);
}

extern "C" void kernel_launch(void* const* d_in, const int* in_sizes, int n_in,
                              void* d_out, int out_size, void* d_ws, size_t ws_size,
                              hipStream_t stream) {
  const void* query  = d_in[0];  const void* prev   = d_in[1];
  const void* prevM  = d_in[2];  const void* first  = d_in[3];
  const void* firstM = d_in[4];  const void* encQw  = d_in[5];
  const void* encQb  = d_in[6];  const void* encMw  = d_in[7];
  const void* encMb  = d_in[8];  const void* keyW   = d_in[9];
  const void* keyB   = d_in[10]; const void* valW   = d_in[11];
  const void* valB   = d_in[12]; const void* dec1W  = d_in[13];
  const void* dec1B  = d_in[14]; const void* dec2W  = d_in[15];
  const void* dec2B  = d_in[16]; const void* clsW   = d_in[17];
  const void* clsB   = d_in[18];

  // ws layout (u16 units); total 28,557,328 u16 = 57.1 MB (round-4 size, fit)
  u16* W = (u16*)d_ws;
  u16* fused = W;                          // [8192][512]
  u16* memv  = W + 4194304;                // [8][256][2048]; later dbuf+decf
  u16* memk  = W + 8388608;                // [8][2048][64]
  u16* qk    = W + 9437184;                // [8192][64]
  u16* wr1   = W + 9961472;                // [256][4608]
  u16* wr2   = W + 11141120;               // [256][2304]
  float* rsinv  = (float*)(W + 11730944);  // 8192 f32
  float* logits = (float*)(W + 11747328);  // 16384 f32
  int* dflag = (int*)(W + 11780096);
  u16* E = W + 11780112;                   // 16,777,216 u16 scratch
  u16* feat3 = E;                          // enc: [3][8192][512]
  u16* kraw3 = E + 12582912;               // enc: [3][8192][64]
  u16* P     = E;                          // attn: [4096][2048] per group
  float* accR = (float*)(E + 8388608);     // attn: [256][4096] f32 (4 MB)
  float* partD = (float*)E;                // dec: [4][256][8192] f32 (33.5 MB)
  u16* dbuf  = memv;                       // dec: [8192][256]
  u16* decf  = memv + 2097152;             // dec: [8192][256]

  dim3 blk(256);
  detect_k<<<dim3(1), blk, 0, stream>>>((const u16*)encQw, dflag);
  wreorder_k<<<dim3(4608), blk, 0, stream>>>(dec1W, wr1, 512, 256 * 4608, dflag);
  wreorder_k<<<dim3(2304), blk, 0, stream>>>(dec2W, wr2, 256, 256 * 2304, dflag);

  // encode: feat3[z][tok][512], z = {first, prev, query}
  {
    PA a{encMw, encQw, 0, 768, 0, 1, 0, 0};
    PBenc b{first, prev, query};
    Epi e{0, feat3, 0, 0, 0, (size_t)8192 * 512, 512, 0, 512, 0, 0, 0,
          encMb, encQb, 1, 0, 0, 1.f, 1, 0};
    mg<PBenc><<<dim3(64, 4, 3), blk, 0, stream>>>(a, b, e, 12, 0, 0, dflag);
  }
  // key+val fused: M=384 (val 0-255, key 256-319)
  {
    PA a{valW, keyW, 0, 512, 256, 0, 0, 63};
    PBws b{feat3, 512, (size_t)8192 * 512, 0};
    Epi e{1, memv, fused, kraw3, 0, 0, 0, 0, 320, 0, 0, 0,
          valB, keyB, 0, firstM, prevM, 1.f, 0, 0};
    mg<PBws><<<dim3(64, 3, 3), blk, 0, stream>>>(a, b, e, 8, 0, 0, dflag);
  }
  keyfix_k<<<dim3(32, 3), blk, 0, stream>>>(kraw3, firstM, prevM, memk, qk, dflag);

  // attention in 2 groups of 4 batches
  for (int g = 0; g < 2; g++) {
    int nb = g * 4096;
    {  // S: P[tloc][m] = exp(0.125 * qk[t,:].memk[b,m,:])
      PA a{memk, 0, 131072, 64, 0, 0, 1, 0};
      PBws b{qk, 64, 0, 0};
      Epi e{0, P, 0, 0, 0, 0, 2048, 0, 1 << 30, nb, 0, 0,
            0, 0, 0, 0, 0, 0.125f, 0, 1};
      mg<PBws><<<dim3(32, 16, 1), blk, 0, stream>>>(a, b, e, 1, 0, nb, dflag);
    }
    stats_k<<<dim3(1024), blk, 0, stream>>>(P, rsinv + nb);
    zero_k<<<dim3(1024), blk, 0, stream>>>((float4*)accR);
    {  // read: accR[c][tloc] += sum_m memv[b][c][m] P[tloc][m]  (split-K x8, atomic)
      PA a{memv, 0, 524288, 2048, 0, 0, 1, 0};
      PBws b{P, 2048, 0, nb};
      Epi e{3, 0, 0, 0, accR, 0, 0, 0, 1 << 30, nb, 0, 4096,
            0, 0, 0, 0, 0, 1.f, 0, 0};
      mg<PBws><<<dim3(32, 2, 8), blk, 0, stream>>>(a, b, e, 4, 1, nb, dflag);
    }
    redux_k<<<dim3(64, 4), blk, 0, stream>>>(accR, 1, 0, 4096, fused, 512, 256,
                                             0, rsinv, nb, 0, dflag);
  }

  // dec1 (split-K x4) -> dbuf
  {
    PA a{wr1, 0, 0, 4608, 0, 0, 1, 0};
    PBc3 b{fused, 512, 9};
    Epi e{2, 0, 0, 0, partD, 0, 0, 0, 1 << 30, 0, (size_t)256 * 8192, 8192,
          0, 0, 0, 0, 0, 1.f, 0, 0};
    mg<PBc3><<<dim3(64, 2, 4), blk, 0, stream>>>(a, b, e, 18, 1, 0, dflag);
  }
  redux_k<<<dim3(128, 4), blk, 0, stream>>>(partD, 4, (size_t)256 * 8192, 8192,
                                            dbuf, 256, 0, dec1B, 0, 0, 1, dflag);
  // dec2 (split-K x4) -> decf
  {
    PA a{wr2, 0, 0, 2304, 0, 0, 1, 0};
    PBc3 b{dbuf, 256, 8};
    Epi e{2, 0, 0, 0, partD, 0, 0, 0, 1 << 30, 0, (size_t)256 * 8192, 8192,
          0, 0, 0, 0, 0, 1.f, 0, 0};
    mg<PBc3><<<dim3(64, 2, 4), blk, 0, stream>>>(a, b, e, 9, 1, 0, dflag);
  }
  redux_k<<<dim3(128, 4), blk, 0, stream>>>(partD, 4, (size_t)256 * 8192, 8192,
                                            decf, 256, 0, dec2B, 0, 0, 1, dflag);

  repcls_k<<<dim3(2048), blk, 0, stream>>>(decf, clsW, clsB, d_out, logits, dflag);
  resize_k<<<dim3(16384), blk, 0, stream>>>(logits, d_out, (size_t)2097152, dflag);
}

// Round 6
// 588.737 us; speedup vs baseline: 1.2816x; 1.2118x over previous
//
#include <hip/hip_runtime.h>
#include <hip/hip_bf16.h>
#include <cstdint>

#define DEV __device__ __forceinline__
typedef __attribute__((ext_vector_type(8))) short short8;
typedef __attribute__((ext_vector_type(4))) float f32x4;
typedef unsigned short u16;

DEV float b2f(u16 u) { union { unsigned int i; float f; } x; x.i = (unsigned)u << 16; return x.f; }
DEV u16 f2b(float f) { __hip_bfloat16 h = __float2bfloat16(f); return *(u16*)&h; }
DEV float rdin(const void* p, size_t i, int isbf) {
  return isbf ? __bfloat162float(((const __hip_bfloat16*)p)[i]) : ((const float*)p)[i];
}
DEV void wrout(void* p, size_t i, float v, int isbf) {
  if (isbf) ((__hip_bfloat16*)p)[i] = __float2bfloat16(v);
  else      ((float*)p)[i] = v;
}
DEV short8 ld8(const void* p, size_t idx, int isbf) {
  if (isbf) return *(const short8*)((const u16*)p + idx);
  const float* f = (const float*)p + idx;
  float4 x = *(const float4*)f, y = *(const float4*)(f + 4);
  short8 r;
  r[0] = f2b(x.x); r[1] = f2b(x.y); r[2] = f2b(x.z); r[3] = f2b(x.w);
  r[4] = f2b(y.x); r[5] = f2b(y.y); r[6] = f2b(y.z); r[7] = f2b(y.w);
  return r;
}

__global__ __launch_bounds__(256) void detect_k(const u16* w, int* flag) {
  __shared__ int cnt[256];
  int tid = threadIdx.x, c = 0;
  for (int i = tid; i < 4096; i += 256) {
    u16 v = w[i];
    int e = (v >> 7) & 0xFF;
    if (v == 0 || (e >= 0x60 && e <= 0x9F)) c++;
  }
  cnt[tid] = c;
  __syncthreads();
  for (int s = 128; s > 0; s >>= 1) { if (tid < s) cnt[tid] += cnt[tid + s]; __syncthreads(); }
  if (tid == 0) *flag = (cnt[0] > 3600) ? 1 : 0;
}

// ---------------- A provider ----------------
struct PA {  // W0/W1; row-split (keyval) or z-select (enc); ws16 = bf16 ws tensor
  const void* W0; const void* W1; size_t bs; int K; int rowsplit; int zsel; int ws16; int rowmax1;
  DEV short8 l8(int row, int k, int b, int zz, int isbf) const {
    const void* W = W0; int r = row;
    if (zsel && zz == 2) W = W1;
    else if (rowsplit && row >= rowsplit) { W = W1; r = row - rowsplit; if (r > rowmax1) r = rowmax1; }
    return ld8(W, (size_t)b * bs + (size_t)r * K + k, ws16 ? 1 : isbf);
  }
};
// ---------------- B providers ----------------
struct PBws {  // bf16 ws tensor: X + zz*zs + t*rs + k (t absolute token)
  const u16* X; int rs; size_t zs;
  DEV short8 l8(int t, int k, int zz, int) const {
    return *(const short8*)(X + (size_t)zz * zs + (size_t)t * rs + k);
  }
};
struct PBenc {  // frames [B][3][512][512], k=(c,ky,kx), token t -> 16x16 patch
  const void* F0; const void* F1; const void* F2;
  DEV short8 l8(int t, int k, int zz, int isbf) const {
    const void* F = zz == 0 ? F0 : (zz == 1 ? F1 : F2);
    int b = t >> 10, pos = t & 1023, y = pos >> 5, x = pos & 31;
    int c = k >> 8, rem = k & 255, ky = rem >> 4, kx = rem & 15;
    return ld8(F, ((((size_t)(b * 3 + c) << 9) + y * 16 + ky) << 9) + x * 16 + kx, isbf);
  }
};
struct PBc3 {  // 3x3 SAME im2col over token-major bf16 [tok][C]; k=(tap, c)
  const u16* X; int C; int shift;
  DEV short8 l8(int t, int k, int, int) const {
    int tap = k >> shift, c0 = k & (C - 1);
    int dy = tap / 3, dx = tap - dy * 3;
    int pos = t & 1023, y = pos >> 5, x = pos & 31;
    int iy = y + dy - 1, ix = x + dx - 1;
    if ((unsigned)iy >= 32u || (unsigned)ix >= 32u) { short8 z = {0,0,0,0,0,0,0,0}; return z; }
    return *(const short8*)(X + (size_t)(((t >> 10) * 1024) + iy * 32 + ix) * C + c0);
  }
};

struct Epi {
  int mode;                 // 0 = token-major via LDS transpose; 1 = keyval direct
  u16 *o16, *o16b, *o16c;
  size_t zs; int ts, moff, mmax;
  const void *bias, *bias2; int bzsel;
  const void *maskA, *maskB;
  const float* rscale;      // [tok] or null
  float scale; int relu, doexp;
  DEV void store1(int m, int t, int z, float v, int isbf) const {  // mode 1
    if (m >= mmax) return;
    int b = t >> 10, pos = t & 1023;
    if (m < 256) {
      v += rdin(bias, m, isbf);
      if (z < 2) {
        const void* mk = z ? maskB : maskA;
        v *= rdin(mk, ((size_t)(b * 512 + (pos >> 5) * 16) << 9) + (pos & 31) * 16, isbf);
        o16[((size_t)(b * 256 + m)) * 2048 + (size_t)z * 1024 + pos] = f2b(v);
      } else {
        o16b[(size_t)t * 512 + m] = f2b(v);
      }
    } else {
      v += rdin(bias2, m - 256, isbf);
      o16c[((size_t)z * 8192 + t) * 64 + (m - 256)] = f2b(v);
    }
  }
};

// ---- MFMA GEMM: 128x128 tile, BK=64, 4 waves (each 64x64), register-prefetch K-loop ----
// BMAP 0: standard row/chunk map. BMAP 1: enc-coalesced (wave = contiguous 1KB image row).
template <class PB, int BMAP>
__global__ __launch_bounds__(256) void mg(PA pa, PB pb, Epi ep, int ktiles, int nbase,
                                          const int* dflag) {
  __shared__ u16 sh[16384];
  u16* As = sh; u16* Bs = sh + 8192;
  int isbf = *dflag;
  int tid = threadIdx.x, lane = tid & 63;
  int col16 = lane & 15, quad = lane >> 4;
  int wv = tid >> 6, wm = wv >> 1, wn = wv & 1;
  int zz = blockIdx.z;
  int n0 = blockIdx.x * 128, m0 = blockIdx.y * 128;
  int bA = (nbase + n0) >> 10;

  f32x4 acc[4][4];
#pragma unroll
  for (int mt = 0; mt < 4; mt++)
#pragma unroll
    for (int nt = 0; nt < 4; nt++)
#pragma unroll
      for (int r = 0; r < 4; r++) acc[mt][nt][r] = 0.f;

  int rA[4], lA[4], rB[4], lB[4], sB[4];
#pragma unroll
  for (int g = 0; g < 4; g++) {
    rA[g] = g * 32 + (tid >> 3);
    lA[g] = (tid & 7) ^ (rA[g] & 7);
    if (BMAP == 0) { rB[g] = rA[g]; lB[g] = lA[g]; }
    else { rB[g] = g * 32 + (tid & 31); lB[g] = tid >> 5; }
    sB[g] = lB[g] ^ (rB[g] & 7);
  }

  short8 ra[4], rb[4];
#pragma unroll
  for (int g = 0; g < 4; g++) {
    ra[g] = pa.l8(m0 + rA[g], lA[g] * 8, bA, zz, isbf);
    rb[g] = pb.l8(nbase + n0 + rB[g], lB[g] * 8, zz, isbf);
  }

  for (int kt = 0; kt < ktiles; kt++) {
    if (kt) __syncthreads();
#pragma unroll
    for (int g = 0; g < 4; g++) {
      *(short8*)&As[(size_t)(g * 256 + tid) * 8] = ra[g];
      *(short8*)&Bs[(size_t)rB[g] * 64 + sB[g] * 8] = rb[g];
    }
    __syncthreads();
    if (kt + 1 < ktiles) {
      int kn = (kt + 1) * 64;
#pragma unroll
      for (int g = 0; g < 4; g++) {
        ra[g] = pa.l8(m0 + rA[g], kn + lA[g] * 8, bA, zz, isbf);
        rb[g] = pb.l8(nbase + n0 + rB[g], kn + lB[g] * 8, zz, isbf);
      }
    }
#pragma unroll
    for (int s = 0; s < 2; s++) {
      short8 af[4], bf[4];
      int cs = ((s * 4 + quad) ^ (col16 & 7)) << 3;
#pragma unroll
      for (int mt = 0; mt < 4; mt++)
        af[mt] = *(const short8*)&As[(wm * 64 + mt * 16 + col16) * 64 + cs];
#pragma unroll
      for (int nt = 0; nt < 4; nt++)
        bf[nt] = *(const short8*)&Bs[(wn * 64 + nt * 16 + col16) * 64 + cs];
#pragma unroll
      for (int mt = 0; mt < 4; mt++)
#pragma unroll
        for (int nt = 0; nt < 4; nt++)
          acc[mt][nt] = __builtin_amdgcn_mfma_f32_16x16x32_bf16(af[mt], bf[nt], acc[mt][nt], 0, 0, 0);
    }
  }

  if (ep.mode == 1) {
#pragma unroll
    for (int mt = 0; mt < 4; mt++)
#pragma unroll
      for (int nt = 0; nt < 4; nt++)
#pragma unroll
        for (int r = 0; r < 4; r++) {
          int m = m0 + wm * 64 + mt * 16 + quad * 4 + r;
          int t = nbase + n0 + wn * 64 + nt * 16 + col16;
          ep.store1(m, t, zz, acc[mt][nt][r], isbf);
        }
    return;
  }
  // mode 0: coalesced token-major store via LDS transpose (two 64-token passes)
  u16* T = sh;  // [64][132]
  const int TS = 132;
  for (int p = 0; p < 2; p++) {
    __syncthreads();
    if (wn == p) {
#pragma unroll
      for (int mt = 0; mt < 4; mt++)
#pragma unroll
        for (int nt = 0; nt < 4; nt++) {
          int tl = nt * 16 + col16;
          int tg = nbase + n0 + p * 64 + tl;
#pragma unroll
          for (int r2 = 0; r2 < 2; r2++) {
            int ml = wm * 64 + mt * 16 + quad * 4 + r2 * 2;
            float v0 = acc[mt][nt][r2 * 2] * ep.scale;
            float v1 = acc[mt][nt][r2 * 2 + 1] * ep.scale;
            if (ep.bias) {
              const void* bp = (ep.bzsel && zz == 2) ? ep.bias2 : ep.bias;
              v0 += rdin(bp, m0 + ml, isbf);
              v1 += rdin(bp, m0 + ml + 1, isbf);
            }
            if (ep.doexp) { v0 = __expf(v0); v1 = __expf(v1); }
            if (ep.rscale) { float rs = ep.rscale[tg]; v0 *= rs; v1 *= rs; }
            if (ep.relu) { v0 = fmaxf(v0, 0.f); v1 = fmaxf(v1, 0.f); }
            unsigned int pk = (unsigned)f2b(v0) | ((unsigned)f2b(v1) << 16);
            *(unsigned int*)&T[tl * TS + ml] = pk;
          }
        }
    }
    __syncthreads();
    {
      int tl = tid >> 2, seg = tid & 3;
      int tg = nbase + n0 + p * 64 + tl;
      u16* op = ep.o16 + (size_t)zz * ep.zs + (size_t)tg * ep.ts + ep.moff + m0;
#pragma unroll
      for (int i = 0; i < 4; i++) {
        int c8 = seg + i * 4;
        short8 v = *(short8*)&T[tl * TS + c8 * 8];
        *(short8*)&op[c8 * 8] = v;
      }
    }
  }
}

// conv3 weight reorder: dst[m][tap*C+c] = src[(m*C+c)*9 + tap]
__global__ __launch_bounds__(256) void wreorder_k(const void* src, u16* dst, int C,
                                                  int total, const int* dflag) {
  int idx = blockIdx.x * 256 + threadIdx.x;
  if (idx >= total) return;
  int isbf = *dflag;
  int nine_c = 9 * C;
  int m = idx / nine_c; int r = idx - m * nine_c;
  int tp = r / C; int c = r - tp * C;
  dst[idx] = f2b(rdin(src, (size_t)(m * C + c) * 9 + tp, isbf));
}

// mask + l2norm over 64 key channels; 3 frames via blockIdx.y
__global__ __launch_bounds__(256) void keyfix_k(const u16* kraw3, const void* mA,
                                                const void* mB, u16* memk, u16* qk,
                                                const int* dflag) {
  int isbf = *dflag;
  int z = blockIdx.y;
  int n = blockIdx.x * 256 + threadIdx.x;
  int b = n >> 10, pos = n & 1023;
  float mv = 1.f;
  if (z == 0) mv = rdin(mA, ((size_t)(b * 512 + (pos >> 5) * 16) << 9) + (pos & 31) * 16, isbf);
  else if (z == 1) mv = rdin(mB, ((size_t)(b * 512 + (pos >> 5) * 16) << 9) + (pos & 31) * 16, isbf);
  const u16* src = kraw3 + ((size_t)z * 8192 + n) * 64;
  float v[64], ss = 0.f;
#pragma unroll
  for (int c = 0; c < 64; c++) { v[c] = b2f(src[c]) * mv; ss += v[c] * v[c]; }
  float inv = 1.f / fmaxf(sqrtf(ss), 1e-12f);
  u16* dst = (z < 2) ? memk + (size_t)(b * 2048 + z * 1024 + pos) * 64 : qk + (size_t)n * 64;
#pragma unroll
  for (int c = 0; c < 64; c++) dst[c] = f2b(v[c] * inv);
}

// row sums of exp'ed P (bf16 [8192][2048]) -> 1/sum
__global__ __launch_bounds__(256) void stats_k(const u16* P, float* rsinv) {
  int tid = threadIdx.x, lane = tid & 63, wv = tid >> 6;
  int row = blockIdx.x * 4 + wv;
  const u16* p = P + (size_t)row * 2048;
  float s = 0.f;
#pragma unroll
  for (int c = 0; c < 4; c++) {
    short8 v = *(const short8*)(p + c * 512 + lane * 8);
#pragma unroll
    for (int j = 0; j < 8; j++) s += b2f((u16)v[j]);
  }
#pragma unroll
  for (int off = 32; off > 0; off >>= 1) s += __shfl_down(s, off);
  if (lane == 0) rsinv[row] = 1.f / s;
}

__global__ __launch_bounds__(256) void repcls_k(const u16* decf, const void* cwgt,
                                                const void* cbias, void* out_rep,
                                                float* logits, const int* dflag) {
  int isbf = *dflag;
  int tid = threadIdx.x, lane = tid & 63, wv = tid >> 6;
  int tok = blockIdx.x * 4 + wv;
  int b = tok >> 10, pos = tok & 1023;
  const u16* src = decf + (size_t)tok * 256;
  int c0 = lane * 4;
  float v[4], ss = 0.f, a0 = 0.f, a1 = 0.f;
#pragma unroll
  for (int j = 0; j < 4; j++) {
    float x = b2f(src[c0 + j]);
    v[j] = x; ss += x * x;
    a0 = fmaf(x, rdin(cwgt, c0 + j, isbf), a0);
    a1 = fmaf(x, rdin(cwgt, 256 + c0 + j, isbf), a1);
  }
#pragma unroll
  for (int off = 32; off > 0; off >>= 1) {
    ss += __shfl_down(ss, off); a0 += __shfl_down(a0, off); a1 += __shfl_down(a1, off);
  }
  ss = __shfl(ss, 0); a0 = __shfl(a0, 0); a1 = __shfl(a1, 0);
  float inv = 1.f / fmaxf(sqrtf(ss), 1e-12f);
#pragma unroll
  for (int j = 0; j < 4; j++)
    wrout(out_rep, ((size_t)(b * 256 + c0 + j) << 10) + pos, v[j] * inv, isbf);
  if (lane == 0) {
    logits[((size_t)(b * 2) << 10) + pos]     = a0 + rdin(cbias, 0, isbf);
    logits[((size_t)(b * 2 + 1) << 10) + pos] = a1 + rdin(cbias, 1, isbf);
  }
}

__global__ __launch_bounds__(256) void resize_k(const float* logits, void* out,
                                                size_t ebase, const int* dflag) {
  int isbf = *dflag;
  int idx = blockIdx.x * 256 + threadIdx.x;
  int ox = idx & 511, oy = (idx >> 9) & 511, c = (idx >> 18) & 1, b = idx >> 19;
  float fy = (oy + 0.5f) * 0.0625f - 0.5f;
  float fx = (ox + 0.5f) * 0.0625f - 0.5f;
  int y0 = (int)floorf(fy), x0 = (int)floorf(fx);
  float wy = fy - y0, wx = fx - x0;
  int y0c = max(y0, 0), y1c = min(y0 + 1, 31);
  int x0c = max(x0, 0), x1c = min(x0 + 1, 31);
  const float* L = logits + ((size_t)(b * 2 + c) << 10);
  float v00 = L[y0c * 32 + x0c], v01 = L[y0c * 32 + x1c];
  float v10 = L[y1c * 32 + x0c], v11 = L[y1c * 32 + x1c];
  float v = (1.f - wy) * ((1.f - wx) * v00 + wx * v01) + wy * ((1.f - wx) * v10 + wx * v11);
  wrout(out, ebase + (size_t)idx, v, isbf);
}

extern "C" void kernel_launch(void* const* d_in, const int* in_sizes, int n_in,
                              void* d_out, int out_size, void* d_ws, size_t ws_size,
                              hipStream_t stream) {
  const void* query  = d_in[0];  const void* prev   = d_in[1];
  const void* prevM  = d_in[2];  const void* first  = d_in[3];
  const void* firstM = d_in[4];  const void* encQw  = d_in[5];
  const void* encQb  = d_in[6];  const void* encMw  = d_in[7];
  const void* encMb  = d_in[8];  const void* keyW   = d_in[9];
  const void* keyB   = d_in[10]; const void* valW   = d_in[11];
  const void* valB   = d_in[12]; const void* dec1W  = d_in[13];
  const void* dec1B  = d_in[14]; const void* dec2W  = d_in[15];
  const void* dec2B  = d_in[16]; const void* clsW   = d_in[17];
  const void* clsB   = d_in[18];

  // ws layout (u16 units); total 28,557,328 u16 = 57.1 MB (proven size)
  u16* W = (u16*)d_ws;
  int* dflag = (int*)W;                       // 16 u16
  float* rsinv  = (float*)(W + 16);           // 8192 f32
  float* logits = (float*)(W + 16400);        // 16384 f32
  u16* B0 = W + 49168;
  u16* fused = B0;                            // [8192][512]
  u16* memv  = B0 + 4194304;                  // [8][256][2048]
  u16* memk  = B0 + 8388608;                  // [8][2048][64]
  u16* qk    = B0 + 9437184;                  // [8192][64]
  u16* wr1   = B0 + 9961472;                  // [256][4608]
  u16* wr2   = B0 + 11141120;                 // [256][2304]
  u16* E     = B0 + 11730944;                 // 16,777,216 u16 scratch
  u16* feat3 = E;                             // enc: [3][8192][512]
  u16* kraw3 = E + 12582912;                  // enc: [3][8192][64]
  u16* P     = E;                             // attn: [8192][2048] bf16 (33.5 MB)
  u16* dbuf  = memv;                          // dec: [8192][256]
  u16* decf  = memv + 2097152;                // dec: [8192][256]

  dim3 blk(256);
  detect_k<<<dim3(1), blk, 0, stream>>>((const u16*)encQw, dflag);
  wreorder_k<<<dim3(4608), blk, 0, stream>>>(dec1W, wr1, 512, 256 * 4608, dflag);
  wreorder_k<<<dim3(2304), blk, 0, stream>>>(dec2W, wr2, 256, 256 * 2304, dflag);

  // encode: feat3[z][tok][512], z = {first, prev, query}; coalesced frame loads (BMAP=1)
  {
    PA a{encMw, encQw, 0, 768, 0, 1, 0, 0};
    PBenc b{first, prev, query};
    Epi e{0, feat3, 0, 0, (size_t)8192 * 512, 512, 0, 512,
          encMb, encQb, 1, 0, 0, 0, 1.f, 1, 0};
    mg<PBenc, 1><<<dim3(64, 4, 3), blk, 0, stream>>>(a, b, e, 12, 0, dflag);
  }
  // key+val fused: M rows 0-255 = val, 256-319 = key (raw)
  {
    PA a{valW, keyW, 0, 512, 256, 0, 0, 63};
    PBws b{feat3, 512, (size_t)8192 * 512};
    Epi e{1, memv, fused, kraw3, 0, 0, 0, 320,
          valB, keyB, 0, firstM, prevM, 0, 1.f, 0, 0};
    mg<PBws, 0><<<dim3(64, 3, 3), blk, 0, stream>>>(a, b, e, 8, 0, dflag);
  }
  keyfix_k<<<dim3(32, 3), blk, 0, stream>>>(kraw3, firstM, prevM, memk, qk, dflag);

  // S: P[t][m] = exp(0.125 * qk[t,:].memk[b,m,:])  (|dot|<=1: no max-sub needed)
  {
    PA a{memk, 0, 131072, 64, 0, 0, 1, 0};
    PBws b{qk, 64, 0};
    Epi e{0, P, 0, 0, 0, 2048, 0, 1 << 30,
          0, 0, 0, 0, 0, 0, 0.125f, 0, 1};
    mg<PBws, 0><<<dim3(64, 16, 1), blk, 0, stream>>>(a, b, e, 1, 0, dflag);
  }
  stats_k<<<dim3(2048), blk, 0, stream>>>(P, rsinv);
  // read: fused[t][256+c] = rsinv[t] * sum_m memv[b][c][m] * P[t][m]   (K=2048)
  {
    PA a{memv, 0, 524288, 2048, 0, 0, 1, 0};
    PBws b{P, 2048, 0};
    Epi e{0, fused, 0, 0, 0, 512, 256, 1 << 30,
          0, 0, 0, 0, 0, rsinv, 1.f, 0, 0};
    mg<PBws, 0><<<dim3(64, 2, 1), blk, 0, stream>>>(a, b, e, 32, 0, dflag);
  }

  // dec1 -> dbuf (K=4608), dec2 -> decf (K=2304), both direct token-major
  {
    PA a{wr1, 0, 0, 4608, 0, 0, 1, 0};
    PBc3 b{fused, 512, 9};
    Epi e{0, dbuf, 0, 0, 0, 256, 0, 1 << 30,
          dec1B, 0, 0, 0, 0, 0, 1.f, 1, 0};
    mg<PBc3, 0><<<dim3(64, 2, 1), blk, 0, stream>>>(a, b, e, 72, 0, dflag);
  }
  {
    PA a{wr2, 0, 0, 2304, 0, 0, 1, 0};
    PBc3 b{dbuf, 256, 8};
    Epi e{0, decf, 0, 0, 0, 256, 0, 1 << 30,
          dec2B, 0, 0, 0, 0, 0, 1.f, 1, 0};
    mg<PBc3, 0><<<dim3(64, 2, 1), blk, 0, stream>>>(a, b, e, 36, 0, dflag);
  }

  repcls_k<<<dim3(2048), blk, 0, stream>>>(decf, clsW, clsB, d_out, logits, dflag);
  resize_k<<<dim3(16384), blk, 0, stream>>>(logits, d_out, (size_t)2097152, dflag);
}